// Round 1
// baseline (1303.276 us; speedup 1.0000x reference)
//
#include <hip/hip_runtime.h>
#include <math.h>

#define BATCH  8
#define CINCH  256
#define HIDC   256
#define NHEADS 8
#define HEADD  32
#define KW     31
#define PADW   15
#define WIDTH  16384

// workspace layout (floats):
//   [0, 2048)      qWk[D][h]        (D=0..255, h=0..7)
//   [2048, 2056)   qWk_b[h]
//   [2056, 2304)   rpe_exp[h][k]    (8*31)
//   [2304, ...)    cost_exp buffer, then vc buffer
#define WS_QWKB 2048
#define WS_RPE  2056
#define WS_BUF  2304

#define FMA4(a, s, v) do { (a).x = fmaf((s),(v).x,(a).x); (a).y = fmaf((s),(v).y,(a).y); \
                           (a).z = fmaf((s),(v).z,(a).z); (a).w = fmaf((s),(v).w,(a).w); } while(0)

__device__ __forceinline__ float f4c(const float4& v, int i) {
  switch (i) { case 0: return v.x; case 1: return v.y; case 2: return v.z; default: return v.w; }
}

// ---------------------------------------------------------------- prep ------
__global__ __launch_bounds__(256) void prep_kernel(
    const float* __restrict__ query, const float* __restrict__ Wk,
    const float* __restrict__ Wkb, const float* __restrict__ rpe,
    float* __restrict__ ws) {
  __shared__ float q_l[256];
  int t = threadIdx.x;
  float qv = query[t];
  float ss = qv * qv;
  #pragma unroll
  for (int m = 16; m >= 1; m >>= 1) ss += __shfl_xor(ss, m, 32);
  qv = qv / (sqrtf(ss) + 1e-6f) * 0.17677669529663687f;  // /(norm+1e-6)/sqrt(32)
  q_l[t] = qv;
  __syncthreads();
  // qWk[D][h] = sum_d q[h,d] * Wk[D, h*32+d]   (thread t = row D)
  const float* wr = Wk + (size_t)t * HIDC;
  #pragma unroll
  for (int h = 0; h < 8; ++h) {
    float s = 0.f;
    #pragma unroll
    for (int d = 0; d < 32; ++d) s = fmaf(q_l[h*32 + d], wr[h*32 + d], s);
    ws[t*8 + h] = s;
  }
  // qWk_b[h] = sum_d Wk_bias[h*32+d] * q[h,d]
  float pb = Wkb[t] * q_l[t];
  #pragma unroll
  for (int m = 16; m >= 1; m >>= 1) pb += __shfl_xor(pb, m, 32);
  if ((t & 31) == 0) ws[WS_QWKB + (t >> 5)] = pb;
  if (t < NHEADS * KW) ws[WS_RPE + t] = __expf(rpe[t]);
}

// ---------------------------------------------------------------- pass1 -----
// per (batch, 64-col tile): cost_exp[8][64] and vc[256][64] -> workspace
__global__ __launch_bounds__(256) void pass1_kernel(
    const float* __restrict__ x, const float* __restrict__ Wv,
    const float* __restrict__ tvb, const float* __restrict__ ws,
    float* __restrict__ costbuf, float* __restrict__ vcbuf,
    int b0, int lo, int hi, int pitch) {
  __shared__ float xs[128 * 64];   // one 128-row chunk of x tile
  __shared__ float qk[2048];       // qWk[D][h]
  __shared__ float part[2048];     // cost partials [q4][h][w]
  __shared__ float ce[8 * 64];     // cost_exp tile

  int t  = threadIdx.x;
  int b  = b0 + blockIdx.y, bb = blockIdx.y;
  int g0 = lo + blockIdx.x * 64;
  int ncol = hi - g0; if (ncol > 64) ncol = 64;

  { // qWk -> LDS (2048 floats = 512 float4)
    const float4* s4 = (const float4*)ws;
    float4* d4 = (float4*)qk;
    d4[t] = s4[t];
    d4[t + 256] = s4[t + 256];
  }

  int q4 = t >> 6, wl = t & 63;
  int tw = q4 << 4, o4 = t & 63;
  float ca[8] = {0,0,0,0,0,0,0,0};
  float4 acc[4][4];
  #pragma unroll
  for (int j = 0; j < 4; ++j)
    #pragma unroll
    for (int c = 0; c < 4; ++c) acc[j][c] = make_float4(0.f,0.f,0.f,0.f);

  const float* xb = x + (size_t)b * CINCH * WIDTH;

  for (int ch = 0; ch < 2; ++ch) {
    __syncthreads();
    // stage 128 rows x 64 cols of x
    #pragma unroll
    for (int it = 0; it < 8; ++it) {
      int r = it * 16 + (t >> 4);
      int c = (t & 15) << 2;
      float4 v = make_float4(0.f,0.f,0.f,0.f);
      if (c < ncol) v = *(const float4*)(xb + (size_t)(ch*128 + r) * WIDTH + g0 + c);
      *(float4*)&xs[r * 64 + c] = v;
    }
    __syncthreads();
    // cost partials: quarter q4 handles local rows [q4*32, q4*32+32)
    {
      const float4* qk4 = (const float4*)qk;
      #pragma unroll
      for (int i = 0; i < 32; ++i) {
        int dl = (q4 << 5) + i;
        float xv = xs[dl * 64 + wl];
        int D = (ch << 7) + dl;
        float4 A = qk4[D*2], Bv = qk4[D*2 + 1];
        ca[0] = fmaf(xv, A.x, ca[0]); ca[1] = fmaf(xv, A.y, ca[1]);
        ca[2] = fmaf(xv, A.z, ca[2]); ca[3] = fmaf(xv, A.w, ca[3]);
        ca[4] = fmaf(xv, Bv.x, ca[4]); ca[5] = fmaf(xv, Bv.y, ca[5]);
        ca[6] = fmaf(xv, Bv.z, ca[6]); ca[7] = fmaf(xv, Bv.w, ca[7]);
      }
    }
    // v GEMM: each thread 4 o-rows x 16 w-cols
    {
      const float4* xs4 = (const float4*)xs;
      for (int D0 = 0; D0 < 128; D0 += 4) {
        int Dg = (ch << 7) + D0;
        float4 wvv[4];
        #pragma unroll
        for (int j = 0; j < 4; ++j)
          wvv[j] = *(const float4*)(Wv + (size_t)(o4 + (j << 6)) * CINCH + Dg);
        #pragma unroll
        for (int dd = 0; dd < 4; ++dd) {
          float4 xv[4];
          #pragma unroll
          for (int c = 0; c < 4; ++c) xv[c] = xs4[(D0 + dd) * 16 + (q4 << 2) + c];
          #pragma unroll
          for (int j = 0; j < 4; ++j) {
            float wj = f4c(wvv[j], dd);
            #pragma unroll
            for (int c = 0; c < 4; ++c) { FMA4(acc[j][c], wj, xv[c]); }
          }
        }
      }
    }
  }

  // reduce cost partials -> cost_exp
  #pragma unroll
  for (int h = 0; h < 8; ++h) part[((q4 << 3) + h) * 64 + wl] = ca[h];
  __syncthreads();
  #pragma unroll
  for (int i = 0; i < 2; ++i) {
    int idx = t + i * 256;
    int h = idx >> 6, w = idx & 63;
    float s = part[h*64 + w] + part[(8+h)*64 + w] + part[(16+h)*64 + w] + part[(24+h)*64 + w]
            + ws[WS_QWKB + h];
    float cexp = __expf(s);
    ce[(h << 6) + w] = cexp;
    if (w < ncol) costbuf[(size_t)(bb*8 + h) * pitch + (g0 - lo) + w] = cexp;
  }
  __syncthreads();

  // vc = cost_exp * (v + bias), store
  #pragma unroll
  for (int j = 0; j < 4; ++j) {
    int o = o4 + (j << 6);
    int h = o >> 5;
    float bias = tvb[o];
    float* dst = vcbuf + (size_t)(bb*256 + o) * pitch + (g0 - lo);
    #pragma unroll
    for (int c = 0; c < 4; ++c) {
      int cc = tw + (c << 2);
      if (cc < ncol) {
        float4 cef = *(const float4*)&ce[(h << 6) + cc];
        float4 a = acc[j][c];
        float4 r;
        r.x = (a.x + bias) * cef.x; r.y = (a.y + bias) * cef.y;
        r.z = (a.z + bias) * cef.z; r.w = (a.w + bias) * cef.w;
        *(float4*)(dst + cc) = r;
      }
    }
  }
}

// ---------------------------------------------------------------- pass2 -----
// per (batch, 32-col tile): windowed sums + divide + Wo GEMM -> out
__global__ __launch_bounds__(256) void pass2_kernel(
    const float* __restrict__ Wo, const float* __restrict__ tob,
    const float* __restrict__ ws, const float* __restrict__ costbuf,
    const float* __restrict__ vcbuf, float* __restrict__ out,
    int b0, int lo, int pitch, int olo) {
  __shared__ float vs[256 * 68];   // vc halo tile, pitch 68 (bank-conflict-free, f4-aligned)
  __shared__ float cs[8 * 68];     // cost_exp halo tile
  __shared__ float rcl[8 * 32];    // 1/sum_c
  __shared__ float rpe_l[8 * 32];  // rpe_exp padded to 32

  int t   = threadIdx.x;
  int b   = b0 + blockIdx.y, bb = blockIdx.y;
  int oc0 = olo + blockIdx.x * 32;
  int base = oc0 - 16;             // global col of LDS col 0

  { int h = t >> 5, k = t & 31;
    rpe_l[t] = (k < KW) ? ws[WS_RPE + h*KW + k] : 0.f; }

  // stage vc halo: 256 rows x 64 cols
  const float* vcb = vcbuf + (size_t)bb * 256 * pitch;
  #pragma unroll
  for (int it = 0; it < 16; ++it) {
    int r = it * 16 + (t >> 4);
    int c = (t & 15) << 2;
    int gw = base + c;
    float4 v;
    if (gw >= 0 && gw + 3 < WIDTH) {
      v = *(const float4*)(vcb + (size_t)r * pitch + (gw - lo));
    } else {
      float tmp[4];
      #pragma unroll
      for (int i = 0; i < 4; ++i) {
        int g = gw + i;
        tmp[i] = (g >= 0 && g < WIDTH) ? vcb[(size_t)r * pitch + (g - lo)] : 0.f;
      }
      v = make_float4(tmp[0], tmp[1], tmp[2], tmp[3]);
    }
    *(float4*)&vs[r * 68 + c] = v;
  }
  // stage cost halo: 8 rows x 64 cols
  if (t < 128) {
    int r = t >> 4;
    int c = (t & 15) << 2;
    int gw = base + c;
    float4 v;
    if (gw >= 0 && gw + 3 < WIDTH) {
      v = *(const float4*)(costbuf + (size_t)(bb*8 + r) * pitch + (gw - lo));
    } else {
      float tmp[4];
      #pragma unroll
      for (int i = 0; i < 4; ++i) {
        int g = gw + i;
        tmp[i] = (g >= 0 && g < WIDTH) ? costbuf[(size_t)(bb*8 + r) * pitch + (g - lo)] : 0.f;
      }
      v = make_float4(tmp[0], tmp[1], tmp[2], tmp[3]);
    }
    *(float4*)&cs[r * 68 + c] = v;
  }
  __syncthreads();

  // sum_c and reciprocal: one (h,w) per thread
  {
    int h = t >> 5, w = t & 31;
    float s = 0.f;
    #pragma unroll
    for (int k = 0; k < KW; ++k) s = fmaf(rpe_l[(h << 5) + k], cs[h*68 + w + 1 + k], s);
    rcl[(h << 5) + w] = 1.0f / s;
  }
  __syncthreads();

  // u = windowed(vc)/sum_c, written in place into vs cols [0,32)
  {
    int rr = t >> 2, w0q = (t & 3) << 3;
    for (int p = 0; p < 4; ++p) {
      int d = (p << 6) + rr;
      int h = d >> 5;
      float xr[40];
      const float4* row4 = (const float4*)&vs[d * 68];
      #pragma unroll
      for (int i = 0; i < 10; ++i) *(float4*)&xr[i << 2] = row4[(w0q >> 2) + i];
      float uv[8];
      #pragma unroll
      for (int w = 0; w < 8; ++w) {
        float a = 0.f;
        #pragma unroll
        for (int k = 0; k < KW; ++k) a = fmaf(rpe_l[(h << 5) + k], xr[w + 1 + k], a);
        uv[w] = a * rcl[(h << 5) + w0q + w];
      }
      __syncthreads();   // all reads of this row-group done before overwrite
      *(float4*)&vs[d * 68 + w0q]     = *(float4*)&uv[0];
      *(float4*)&vs[d * 68 + w0q + 4] = *(float4*)&uv[4];
    }
  }
  __syncthreads();

  // out GEMM: each thread 4 o-rows x 8 w-cols
  {
    int q4 = t >> 6, o4 = t & 63;
    int tw = q4 << 3;
    float4 acc[4][2];
    #pragma unroll
    for (int j = 0; j < 4; ++j) { acc[j][0] = make_float4(0,0,0,0); acc[j][1] = make_float4(0,0,0,0); }
    const float4* vs4 = (const float4*)vs;
    for (int D0 = 0; D0 < 256; D0 += 4) {
      float4 wvv[4];
      #pragma unroll
      for (int j = 0; j < 4; ++j)
        wvv[j] = *(const float4*)(Wo + (size_t)(o4 + (j << 6)) * HIDC + D0);
      #pragma unroll
      for (int dd = 0; dd < 4; ++dd) {
        float4 x0 = vs4[(D0 + dd) * 17 + (q4 << 1)];
        float4 x1 = vs4[(D0 + dd) * 17 + (q4 << 1) + 1];
        #pragma unroll
        for (int j = 0; j < 4; ++j) {
          float wj = f4c(wvv[j], dd);
          FMA4(acc[j][0], wj, x0);
          FMA4(acc[j][1], wj, x1);
        }
      }
    }
    #pragma unroll
    for (int j = 0; j < 4; ++j) {
      int o = o4 + (j << 6);
      float bias = tob[o];
      float* dst = out + ((size_t)b * HIDC + o) * WIDTH + oc0 + tw;
      float4 r0 = acc[j][0], r1 = acc[j][1];
      r0.x += bias; r0.y += bias; r0.z += bias; r0.w += bias;
      r1.x += bias; r1.y += bias; r1.z += bias; r1.w += bias;
      *(float4*)(dst)     = r0;
      *(float4*)(dst + 4) = r1;
    }
  }
}

// ---------------------------------------------------------------- launch ----
extern "C" void kernel_launch(void* const* d_in, const int* in_sizes, int n_in,
                              void* d_out, int out_size, void* d_ws, size_t ws_size,
                              hipStream_t stream) {
  const float* x     = (const float*)d_in[0];
  const float* query = (const float*)d_in[1];
  const float* Wk    = (const float*)d_in[2];
  const float* Wkb   = (const float*)d_in[3];
  const float* rpe   = (const float*)d_in[4];
  const float* Wv    = (const float*)d_in[5];
  const float* tvb   = (const float*)d_in[6];
  const float* Wo    = (const float*)d_in[7];
  const float* tob   = (const float*)d_in[8];
  float* out = (float*)d_out;
  float* ws  = (float*)d_ws;

  prep_kernel<<<1, 256, 0, stream>>>(query, Wk, Wkb, rpe, ws);

  float* costb = ws + WS_BUF;
  size_t need1 = ((size_t)WS_BUF + (size_t)BATCH*8*WIDTH + (size_t)BATCH*256*WIDTH) * sizeof(float);
  size_t need2 = ((size_t)WS_BUF + (size_t)8*WIDTH + (size_t)256*WIDTH) * sizeof(float);

  if (ws_size >= need1) {
    float* vcb = costb + (size_t)BATCH * 8 * WIDTH;
    pass1_kernel<<<dim3(WIDTH/64, BATCH), 256, 0, stream>>>(x, Wv, tvb, ws, costb, vcb, 0, 0, WIDTH, WIDTH);
    pass2_kernel<<<dim3(WIDTH/32, BATCH), 256, 0, stream>>>(Wo, tob, ws, costb, vcb, out, 0, 0, WIDTH, 0);
  } else if (ws_size >= need2) {
    float* vcb = costb + (size_t)8 * WIDTH;
    for (int b = 0; b < BATCH; ++b) {
      pass1_kernel<<<dim3(WIDTH/64, 1), 256, 0, stream>>>(x, Wv, tvb, ws, costb, vcb, b, 0, WIDTH, WIDTH);
      pass2_kernel<<<dim3(WIDTH/32, 1), 256, 0, stream>>>(Wo, tob, ws, costb, vcb, out, b, 0, WIDTH, 0);
    }
  } else {
    int CW = 2048;
    size_t need3 = ((size_t)WS_BUF + (size_t)(8 + 256) * (CW + 32)) * sizeof(float);
    if (ws_size < need3) CW = 256;
    float* vcb = costb + (size_t)8 * (CW + 32);
    for (int b = 0; b < BATCH; ++b) {
      for (int c0 = 0; c0 < WIDTH; c0 += CW) {
        int lo = c0 - 16; if (lo < 0) lo = 0;
        int hi = c0 + CW + 16; if (hi > WIDTH) hi = WIDTH;
        int pitch = hi - lo;
        pass1_kernel<<<dim3((pitch + 63)/64, 1), 256, 0, stream>>>(x, Wv, tvb, ws, costb, vcb, b, lo, hi, pitch);
        pass2_kernel<<<dim3(CW/32, 1), 256, 0, stream>>>(Wo, tob, ws, costb, vcb, out, b, lo, pitch, c0);
      }
    }
  }
}

// Round 2
// 642.859 us; speedup vs baseline: 2.0273x; 2.0273x over previous
//
#include <hip/hip_runtime.h>
#include <hip/hip_bf16.h>
#include <math.h>

#define BATCH  8
#define NHEADS 8
#define KW     31
#define W      16384

// ---- workspace byte offsets ----
// floats at base: qWk [256][8] (2048 f), qWk_b [8], rpe_exp [8][31]
#define WS_QWKB 2048
#define WS_RPE  2056
#define OFF_WVH 9216                       // Wv bf16 [256][256]  (131072 B)
#define OFF_WOH (OFF_WVH + 131072)         // Wo bf16 [256][256]
#define OFF_CE  (OFF_WOH + 131072)         // cost_exp fp32 [2][8][W]  (1 MiB)
#define OFF_XT  (OFF_CE + 2*8*W*4)         // xT bf16 [2][W][2][256] / vc fp32 [2][W][256]  (32 MiB)
#define OFF_U   (OFF_XT + (size_t)2*W*1024)// u  bf16 [2][W][2][256]  (32 MiB)

typedef __attribute__((ext_vector_type(8))) short  short8;
typedef __attribute__((ext_vector_type(4))) float  f32x4;

__device__ __forceinline__ float f4c(const float4& v, int i) {
  switch (i) { case 0: return v.x; case 1: return v.y; case 2: return v.z; default: return v.w; }
}
__device__ __forceinline__ unsigned short f2bf(float f) {
  union { __hip_bfloat16 h; unsigned short u; } cv; cv.h = __float2bfloat16(f); return cv.u;
}
__device__ __forceinline__ float bf2f(unsigned short u) {
  union { __hip_bfloat16 h; unsigned short u; } cv; cv.u = u; return __bfloat162float(cv.h);
}

// ---------------------------------------------------------------- prep ------
// block 0: qWk [256][8], qWk_b[8], rpe_exp; blocks 1-4: Wv->bf16; 5-8: Wo->bf16
__global__ __launch_bounds__(256) void prep_kernel(
    const float* __restrict__ query, const float* __restrict__ Wk,
    const float* __restrict__ Wkb, const float* __restrict__ rpe,
    const float* __restrict__ Wv, const float* __restrict__ Wo,
    float* __restrict__ ws, unsigned short* __restrict__ WvH,
    unsigned short* __restrict__ WoH) {
  int t = threadIdx.x, bid = blockIdx.x;
  if (bid == 0) {
    __shared__ float q_l[256];
    float qv = query[t];
    float ss = qv * qv;
    #pragma unroll
    for (int m = 16; m >= 1; m >>= 1) ss += __shfl_xor(ss, m, 32);
    qv = qv / (sqrtf(ss) + 1e-6f) * 0.17677669529663687f;  // /(norm+1e-6)/sqrt(32)
    q_l[t] = qv;
    __syncthreads();
    const float* wr = Wk + (size_t)t * 256;
    #pragma unroll
    for (int h = 0; h < 8; ++h) {
      float s = 0.f;
      #pragma unroll
      for (int d = 0; d < 32; ++d) s = fmaf(q_l[h*32 + d], wr[h*32 + d], s);
      ws[t*8 + h] = s;
    }
    float pb = Wkb[t] * q_l[t];
    #pragma unroll
    for (int m = 16; m >= 1; m >>= 1) pb += __shfl_xor(pb, m, 32);
    if ((t & 31) == 0) ws[WS_QWKB + (t >> 5)] = pb;
    if (t < NHEADS * KW) ws[WS_RPE + t] = __expf(rpe[t]);
  } else {
    const float* src = (bid <= 4) ? Wv : Wo;
    unsigned short* dst = (bid <= 4) ? WvH : WoH;
    int seg = (bid - 1) & 3;
    int base4 = seg * 4096;   // float4 index base (16384 floats per segment)
    #pragma unroll
    for (int it = 0; it < 16; ++it) {
      int i4 = base4 + t + 256 * it;
      float4 v = ((const float4*)src)[i4];
      ushort4 o;
      o.x = f2bf(v.x); o.y = f2bf(v.y); o.z = f2bf(v.z); o.w = f2bf(v.w);
      ((ushort4*)dst)[i4] = o;
    }
  }
}

// ------------------------------------------------------- K2: transpose ------
// per (64-w tile, batch-in-chunk): xT[w][hi|lo] bf16 + cost_exp fp32
__global__ __launch_bounds__(256, 2) void transpose_kernel(
    const float* __restrict__ x, const float* __restrict__ ws,
    unsigned short* __restrict__ xT, float* __restrict__ ceout, int b0) {
  __shared__ float xs[64 * 260];   // [w][D] fp32, pitch 260
  int t = threadIdx.x;
  int bb = blockIdx.y, b = b0 + bb;
  int w0 = blockIdx.x * 64;

  // P1: load x[D][w] tiles, 4x4 register transpose, write xs[w][D]
  {
    int r = t >> 4, c2 = t & 15;
    #pragma unroll
    for (int db = 0; db < 4; ++db) {
      float4 v0 = *(const float4*)(x + ((size_t)b*256 + db*64 + r*4 + 0)*W + w0 + c2*4);
      float4 v1 = *(const float4*)(x + ((size_t)b*256 + db*64 + r*4 + 1)*W + w0 + c2*4);
      float4 v2 = *(const float4*)(x + ((size_t)b*256 + db*64 + r*4 + 2)*W + w0 + c2*4);
      float4 v3 = *(const float4*)(x + ((size_t)b*256 + db*64 + r*4 + 3)*W + w0 + c2*4);
      #pragma unroll
      for (int i = 0; i < 4; ++i) {
        float4 tv = make_float4(f4c(v0,i), f4c(v1,i), f4c(v2,i), f4c(v3,i));
        *(float4*)&xs[(c2*4 + i)*260 + db*64 + r*4] = tv;
      }
    }
  }
  __syncthreads();

  // P2: per-thread (w, 64-D run): cost partials + bf16 hi/lo split + store xT
  int w = t & 63, q = t >> 6;
  int qu = __builtin_amdgcn_readfirstlane(q);
  float ca[8] = {0,0,0,0,0,0,0,0};
  {
    const float* xrow = &xs[w*260 + qu*64];
    unsigned short* xtd = xT + ((size_t)bb*W + w0 + w)*512 + qu*64;
    const float* qkb = ws + (size_t)qu*64*8;
    #pragma unroll
    for (int k8 = 0; k8 < 8; ++k8) {
      f32x4 u0 = *(const f32x4*)(xrow + 8*k8);
      f32x4 u1 = *(const f32x4*)(xrow + 8*k8 + 4);
      const float* qr = qkb + 8*k8*8;
      #pragma unroll
      for (int e = 0; e < 4; ++e) {
        #pragma unroll
        for (int h = 0; h < 8; ++h) {
          ca[h] = fmaf(u0[e], qr[e*8 + h], ca[h]);
          ca[h] = fmaf(u1[e], qr[(e+4)*8 + h], ca[h]);
        }
      }
      short8 hv, lv;
      #pragma unroll
      for (int e = 0; e < 4; ++e) {
        unsigned short h0 = f2bf(u0[e]); unsigned short h1 = f2bf(u1[e]);
        hv[e]   = (short)h0;  hv[e+4] = (short)h1;
        lv[e]   = (short)f2bf(u0[e] - bf2f(h0));
        lv[e+4] = (short)f2bf(u1[e] - bf2f(h1));
      }
      // interleave back to natural order: hv holds e0..e3 then e4..e7 -> need D order 0..7
      short8 hs, ls;
      hs[0]=hv[0]; hs[1]=hv[1]; hs[2]=hv[2]; hs[3]=hv[3]; hs[4]=hv[4]; hs[5]=hv[5]; hs[6]=hv[6]; hs[7]=hv[7];
      ls[0]=lv[0]; ls[1]=lv[1]; ls[2]=lv[2]; ls[3]=lv[3]; ls[4]=lv[4]; ls[5]=lv[5]; ls[6]=lv[6]; ls[7]=lv[7];
      *(short8*)(xtd + 8*k8)       = hs;
      *(short8*)(xtd + 256 + 8*k8) = ls;
    }
  }
  __syncthreads();
  // P3: exchange cost partials through xs[0..2048)
  #pragma unroll
  for (int h = 0; h < 8; ++h) xs[(q*64 + w)*8 + h] = ca[h];
  __syncthreads();
  // P4: reduce, exp, store
  #pragma unroll
  for (int s = 0; s < 2; ++s) {
    int idx = t + 256*s;
    int h = idx >> 6, ww = idx & 63;
    float sum = xs[(ww)*8 + h] + xs[(64+ww)*8 + h] + xs[(128+ww)*8 + h] + xs[(192+ww)*8 + h]
              + ws[WS_QWKB + h];
    ceout[((size_t)bb*8 + h)*W + w0 + ww] = __expf(sum);
  }
}

// ------------------------------------------------- K3/K5: MFMA GEMM ---------
// C[o][w] = A(bf16 256x256) . B(hi+lo bf16, [w][hi256|lo256])
// MODE 0: vc epilogue (mult by ce, +bias first), write fp32 in-place over Bact
// MODE 1: out epilogue (+bias), write d_out [b][o][W]
template<int MODE>
__global__ __launch_bounds__(256, 2) void gemm_kernel(
    const unsigned short* __restrict__ A, const float* __restrict__ bias,
    const float* __restrict__ cost, unsigned short* Bact,
    float* outp, int b0) {
  __shared__ float smem[17408];     // staging (128 rows x 528B) / assembly
  __shared__ float ceL[512];
  __shared__ float biasL[256];
  unsigned short* smem_u = (unsigned short*)smem;

  int t = threadIdx.x;
  int bb = blockIdx.y;
  int w0 = blockIdx.x * 64;

  biasL[t] = bias[t];
  if (MODE == 0) {
    #pragma unroll
    for (int s = 0; s < 2; ++s) {
      int i = t + 256*s;
      ceL[i] = cost[((size_t)(bb*8 + (i >> 6)))*W + w0 + (i & 63)];
    }
  }
  // stage B tile: 64 w x 1024B (hi row, lo row) -> LDS rows pitch 264 ushort
  {
    const unsigned short* src = Bact + ((size_t)bb*W + w0)*512;
    #pragma unroll
    for (int it = 0; it < 16; ++it) {
      int idx = t + 256*it;
      int r = idx >> 5, col = (idx & 31) * 8;
      short8 v = *(const short8*)(src + (size_t)idx*8);
      *(short8*)(smem_u + r*264 + col) = v;
    }
  }
  __syncthreads();

  int wid = t >> 6, quad = (t >> 4) & 3, m = t & 15;
  f32x4 acc[4][4];
  #pragma unroll
  for (int j = 0; j < 4; ++j)
    #pragma unroll
    for (int c = 0; c < 4; ++c) acc[j][c] = (f32x4){0.f, 0.f, 0.f, 0.f};

  #pragma unroll
  for (int kk = 0; kk < 8; ++kk) {
    int ko = kk*32 + quad*8;
    short8 a[4], bh[4], bl[4];
    #pragma unroll
    for (int j = 0; j < 4; ++j)
      a[j] = *(const short8*)(A + (size_t)(64*wid + 16*j + m)*256 + ko);
    #pragma unroll
    for (int c = 0; c < 4; ++c) {
      int row = 2*(16*c + m);
      bh[c] = *(const short8*)(smem_u + row*264 + ko);
      bl[c] = *(const short8*)(smem_u + (row+1)*264 + ko);
    }
    #pragma unroll
    for (int j = 0; j < 4; ++j)
      #pragma unroll
      for (int c = 0; c < 4; ++c) {
        acc[j][c] = __builtin_amdgcn_mfma_f32_16x16x32_bf16(a[j], bh[c], acc[j][c], 0, 0, 0);
        acc[j][c] = __builtin_amdgcn_mfma_f32_16x16x32_bf16(a[j], bl[c], acc[j][c], 0, 0, 0);
      }
  }
  __syncthreads();

  if (MODE == 0) {
    // vc = ce[h][w] * (v + bias) -> smem [w][o] pitch 260 -> global fp32 (in place)
    #pragma unroll
    for (int j = 0; j < 4; ++j) {
      int ob = 64*wid + 16*j + 4*quad;
      int h = (64*wid + 16*j) >> 5;
      #pragma unroll
      for (int c = 0; c < 4; ++c) {
        int w = 16*c + m;
        float ce = ceL[h*64 + w];
        f32x4 r;
        #pragma unroll
        for (int i = 0; i < 4; ++i) r[i] = (acc[j][c][i] + biasL[ob + i]) * ce;
        *(f32x4*)(smem + w*260 + ob) = r;
      }
    }
    __syncthreads();
    float* vcg = (float*)Bact;
    size_t rowbase = (size_t)bb*W + w0;
    int w = t >> 2;
    #pragma unroll
    for (int k = 0; k < 16; ++k) {
      int oq = (t & 3)*64 + 4*k;
      f32x4 v = *(const f32x4*)(smem + w*260 + oq);
      *(f32x4*)(vcg + (rowbase + w)*256 + oq) = v;
    }
  } else {
    // out = v + bias -> smem [o][w] pitch 68 -> d_out
    #pragma unroll
    for (int j = 0; j < 4; ++j) {
      int ob = 64*wid + 16*j + 4*quad;
      #pragma unroll
      for (int c = 0; c < 4; ++c) {
        int w = 16*c + m;
        #pragma unroll
        for (int i = 0; i < 4; ++i) smem[(ob + i)*68 + w] = acc[j][c][i] + biasL[ob + i];
      }
    }
    __syncthreads();
    float* og = outp + (size_t)(b0 + bb)*256*W;
    #pragma unroll
    for (int i = 0; i < 4; ++i) {
      int o = (t >> 2) + 64*i;
      int c4 = t & 3;
      #pragma unroll
      for (int k = 0; k < 4; ++k) {
        int w = (c4 + 4*k)*4;
        f32x4 v = *(const f32x4*)(smem + o*68 + w);
        *(f32x4*)(og + (size_t)o*W + w0 + w) = v;
      }
    }
  }
}

// ------------------------------------------------------- K4: conv -----------
// depthwise K=31 windowed sums of vc and ce; u = sum_v/sum_c -> bf16 hi/lo
__global__ __launch_bounds__(256, 2) void conv_kernel(
    const float* __restrict__ vc, const float* __restrict__ costexp,
    const float* __restrict__ rpe_ws, unsigned short* __restrict__ u) {
  __shared__ float vcl[94 * 132];   // [w'][128 d] fp32, pitch 132
  __shared__ float cel[8 * 96];     // ce halo
  __shared__ float rcl[8 * 64];     // 1/sum_c
  __shared__ float rpel[8 * 32];

  int t = threadIdx.x;
  int half = blockIdx.y, bb = blockIdx.z;
  int w0 = blockIdx.x * 64;

  rpel[t] = ((t & 31) < KW) ? rpe_ws[(t >> 5)*KW + (t & 31)] : 0.f;
  // stage ce halo [8][94]
  #pragma unroll
  for (int it = 0; it < 3; ++it) {
    int idx = t + 256*it;
    int h = idx / 96, c = idx % 96;
    if (h < 8) {
      int gw = w0 - 15 + c;
      cel[idx] = (c < 94 && gw >= 0 && gw < W) ? costexp[((size_t)bb*8 + h)*W + gw] : 0.f;
    }
  }
  // stage vc tile [94][128]
  #pragma unroll
  for (int it = 0; it < 12; ++it) {
    int idx = t + 256*it;
    int r = idx >> 5, c4 = (idx & 31)*4;
    if (r < 94) {
      int gw = w0 - 15 + r;
      float4 v = make_float4(0.f, 0.f, 0.f, 0.f);
      if (gw >= 0 && gw < W)
        v = *(const float4*)(vc + ((size_t)bb*W + gw)*256 + half*128 + c4);
      *(float4*)&vcl[r*132 + c4] = v;
    }
  }
  __syncthreads();

  // rc = 1/sum_c for all (h, w)
  #pragma unroll
  for (int s = 0; s < 2; ++s) {
    int idx = t + 256*s;
    int h = idx >> 6, w = idx & 63;
    float acc = 0.f;
    #pragma unroll
    for (int k = 0; k < KW; ++k) acc = fmaf(rpel[h*32 + k], cel[h*96 + w + k], acc);
    rcl[h*64 + w] = 1.0f / acc;
  }
  __syncthreads();

  int p = t & 63, g = t >> 6;
  int hh = half*4 + (p >> 4);
  float rp[KW];
  #pragma unroll
  for (int k = 0; k < KW; ++k) rp[k] = rpel[hh*32 + k];

  float ax[16], ay[16];
  #pragma unroll
  for (int i = 0; i < 16; ++i) { ax[i] = 0.f; ay[i] = 0.f; }
  #pragma unroll
  for (int s = 0; s < 46; ++s) {
    float2 v = *(const float2*)&vcl[(16*g + s)*132 + 2*p];
    #pragma unroll
    for (int i = 0; i < 16; ++i) {
      int k = s - i;
      if (k >= 0 && k < KW) {
        ax[i] = fmaf(rp[k], v.x, ax[i]);
        ay[i] = fmaf(rp[k], v.y, ay[i]);
      }
    }
  }
  #pragma unroll
  for (int i = 0; i < 16; ++i) {
    float rc = rcl[hh*64 + 16*g + i];
    float ux = ax[i] * rc, uy = ay[i] * rc;
    unsigned short hx = f2bf(ux), hy = f2bf(uy);
    unsigned short lx = f2bf(ux - bf2f(hx)), ly = f2bf(uy - bf2f(hy));
    unsigned short* ud = u + ((size_t)bb*W + w0 + 16*g + i)*512 + half*128 + 2*p;
    ushort2 hvv; hvv.x = hx; hvv.y = hy;
    ushort2 lvv; lvv.x = lx; lvv.y = ly;
    *(ushort2*)(ud)       = hvv;
    *(ushort2*)(ud + 256) = lvv;
  }
}

// ---------------------------------------------------------------- launch ----
extern "C" void kernel_launch(void* const* d_in, const int* in_sizes, int n_in,
                              void* d_out, int out_size, void* d_ws, size_t ws_size,
                              hipStream_t stream) {
  const float* x     = (const float*)d_in[0];
  const float* query = (const float*)d_in[1];
  const float* Wk    = (const float*)d_in[2];
  const float* Wkb   = (const float*)d_in[3];
  const float* rpe   = (const float*)d_in[4];
  const float* Wv    = (const float*)d_in[5];
  const float* tvb   = (const float*)d_in[6];
  const float* Wo    = (const float*)d_in[7];
  const float* tob   = (const float*)d_in[8];
  float* out = (float*)d_out;
  char* wsb  = (char*)d_ws;
  float* wsf = (float*)d_ws;

  unsigned short* WvH = (unsigned short*)(wsb + OFF_WVH);
  unsigned short* WoH = (unsigned short*)(wsb + OFF_WOH);
  float*          ceB = (float*)(wsb + OFF_CE);
  unsigned short* xT  = (unsigned short*)(wsb + OFF_XT);
  unsigned short* uB  = (unsigned short*)(wsb + OFF_U);

  prep_kernel<<<9, 256, 0, stream>>>(query, Wk, Wkb, rpe, Wv, Wo, wsf, WvH, WoH);

  for (int c = 0; c < 4; ++c) {
    int b0 = c * 2;
    transpose_kernel<<<dim3(256, 2), 256, 0, stream>>>(x, wsf, xT, ceB, b0);
    gemm_kernel<0><<<dim3(256, 2), 256, 0, stream>>>(WvH, tvb, ceB, xT, nullptr, b0);
    conv_kernel<<<dim3(256, 2, 2), 256, 0, stream>>>((const float*)xT, ceB, wsf + WS_RPE, uB);
    gemm_kernel<1><<<dim3(256, 2), 256, 0, stream>>>(WoH, tob, nullptr, uB, out, b0);
  }
}